// Round 3
// baseline (88.690 us; speedup 1.0000x reference)
//
#include <hip/hip_runtime.h>
#include <hip/hip_bf16.h>

// KANLinear as fragment-direct bf16 MFMA GEMM, 2-dispatch structure (R3):
//   y = hatA @ W''^T + skip_b
//   R2 post-mortem: deleting a whole K-split changed dur by 0.0 us => timed
//   window is fixed-overhead dominated (40.5us ws-poison fill + ~6-9us per
//   dispatch gap). Lever = dispatch count. R3 removes kan_reduce by removing
//   split-K: each gemm block computes FULL K=4096 for a 32row x 64col tile
//   and writes out+bias directly. No partials, no atomics, no fences (R1's
//   L2-nuke mistake avoided) - the prep->gemm launch boundary is the sync.
// Skip fold (verified R1/R2): sum_k hat_k(t)*grid_k = clamp(x) exactly, so
//   prep bakes W''[o][d*16+k] = values[o,d,k] + grid_k*skip_w[o,d].
// Grid: 64 mi x 4 oq = 256 blocks (1/CU), 4 waves; wave = 32 rows x 16 cols,
//   acc[2] (two 16x16 row-frags), 4 MFMA / 64-k step, 64 steps.
//   mi = blockIdx&63 => same-mi oq-siblings land on the SAME XCD (round-robin
//   %8), so x row-panels are XCD-L2-local; Wf (2MB) L2-caches everywhere.
// A-tile LDS is XOR-swizzled: old row*128B layout = 16-way bank conflict on
//   ds_read_b128 A-frags (G4 pattern); swizzle slot^=(row&7) fixes the read
//   path (critical now: 1 wave/SIMD, no TLP to hide LDS stalls).
// B-prefetch 2 steps deep (~2x170cyc lead > ~200cyc L2 latency); bb0/bb1 and
//   aLds[0/1] indexed with compile-time constants only (no scratch spills).

namespace {
constexpr int Bsz  = 2048;
constexpr int Din  = 256;
constexpr int Dout = 256;
constexpr int Kn   = 16;
constexpr int KKNOT = Din * Kn;        // 4096 = full K (skip folded in)
constexpr int KB    = KKNOT / 32;      // 128 k-blocks of 32
constexpr float INV_H = 7.5f;          // 1 / (2/15)
constexpr float Hgrid = 2.0f / 15.0f;

constexpr int NSTEP = KKNOT / 64;      // 64 k-steps of 64 (2 kblocks)
constexpr int SXS   = 260;             // sx row stride (floats), conflict-free
}

typedef __attribute__((ext_vector_type(8))) short shortx8;   // 8 bf16 = 4 VGPR
typedef __attribute__((ext_vector_type(4))) float floatx4;   // MFMA acc

__device__ __forceinline__ unsigned int f2bf(float f) {
  __hip_bfloat16 h = __float2bfloat16(f);
  return (unsigned int)*reinterpret_cast<unsigned short*>(&h);
}
__device__ __forceinline__ float clamp1(float v) {
  return fminf(1.f, fmaxf(-1.f, v));
}
// Pack two pre-rounded f32 bit patterns (already +0x8000) into bf16x2.
__device__ __forceinline__ unsigned int packbf(unsigned int e0, unsigned int e1) {
  return (e1 & 0xffff0000u) | (e0 >> 16);
}
__device__ __forceinline__ unsigned int rnd(float f) {
  return __float_as_uint(f) + 0x8000u;
}

// Build 8 hat weights for one dim (hats h0..h0+7) -> 16B of bf16 into LDS.
__device__ __forceinline__ void buildA(unsigned short* dst, float xv, float h0) {
  const float t = (clamp1(xv) + 1.f) * INV_H;
  unsigned int e[8];
  #pragma unroll
  for (int h = 0; h < 8; ++h)
    e[h] = rnd(fmaxf(0.f, 1.f - fabsf(t - (h0 + (float)h))));
  *(uint4*)dst = make_uint4(packbf(e[0], e[1]), packbf(e[2], e[3]),
                            packbf(e[4], e[5]), packbf(e[6], e[7]));
}

// One 64-k step: 4 swizzled A-frag reads + 4 MFMA into two row accs.
__device__ __forceinline__ void mstep(const unsigned short* aBuf,
                                      const uint4 b0, const uint4 b1,
                                      const int o00, const int o01,
                                      const int o10, const int o11,
                                      floatx4& acc0, floatx4& acc1) {
  const shortx8 a00 = *(const shortx8*)(aBuf + o00);
  const shortx8 a10 = *(const shortx8*)(aBuf + o10);
  const shortx8 a01 = *(const shortx8*)(aBuf + o01);
  const shortx8 a11 = *(const shortx8*)(aBuf + o11);
  union { uint4 u; shortx8 s; } c0, c1;
  c0.u = b0; c1.u = b1;
  acc0 = __builtin_amdgcn_mfma_f32_16x16x32_bf16(a00, c0.s, acc0, 0, 0, 0);
  acc1 = __builtin_amdgcn_mfma_f32_16x16x32_bf16(a10, c0.s, acc1, 0, 0, 0);
  acc0 = __builtin_amdgcn_mfma_f32_16x16x32_bf16(a01, c1.s, acc0, 0, 0, 0);
  acc1 = __builtin_amdgcn_mfma_f32_16x16x32_bf16(a11, c1.s, acc1, 0, 0, 0);
}

// --- Prep: fold skip into values, permute into B-fragment order.
//     Grid: 512 blocks x 256.  chunk(kb,og,q,n), lane = q*16+n matches gemm.
__global__ __launch_bounds__(256) void kan_prep(
    const float* __restrict__ values, const float* __restrict__ skip_w,
    unsigned short* __restrict__ Wf) {
  const int tid = blockIdx.x * 256 + threadIdx.x;   // 131072 total
  const int q  = tid & 3;
  const int n  = (tid >> 2) & 15;
  const int og = (tid >> 6) & 15;
  const int kb = tid >> 10;                          // 0..127
  const int o  = og * 16 + n;
  const int k0 = kb * 32 + q * 8;                    // 8 consecutive k, same dim
  const int d  = k0 >> 4;
  const float h0 = (float)(k0 & 15);                 // 0 or 8
  const float sw = skip_w[o * Din + d];
  const float* src = values + (size_t)o * KKNOT + k0;
  const float4 v0 = *(const float4*)src;
  const float4 v1 = *(const float4*)(src + 4);
  float e[8] = {v0.x, v0.y, v0.z, v0.w, v1.x, v1.y, v1.z, v1.w};
  #pragma unroll
  for (int j = 0; j < 8; ++j)
    e[j] = fmaf(-1.f + (h0 + (float)j) * Hgrid, sw, e[j]);  // + grid_k * skip_w
  const size_t chunk = (size_t)kb * 1024 + og * 64 + q * 16 + n;
  *(uint4*)(Wf + chunk * 8) = make_uint4(
      f2bf(e[0]) | (f2bf(e[1]) << 16), f2bf(e[2]) | (f2bf(e[3]) << 16),
      f2bf(e[4]) | (f2bf(e[5]) << 16), f2bf(e[6]) | (f2bf(e[7]) << 16));
}

// --- Full-K GEMM, direct out+bias. Grid = 256 blocks x 256 thr (4 waves).
__global__ __launch_bounds__(256) void kan_gemm_full(
    const float* __restrict__ x, const unsigned short* __restrict__ Wf,
    const float* __restrict__ skip_b, float* __restrict__ out) {
  __shared__ float sx[32 * SXS];                            // full x slice, 33 KB
  __shared__ __align__(16) unsigned short aLds[2][32 * 64]; // A tiles, 2x4 KB

  const int tid  = threadIdx.x;
  const int wave = tid >> 6, lane = tid & 63;
  const int mi   = blockIdx.x & 63;              // same-mi siblings: same XCD
  const int oq   = blockIdx.x >> 6;              // 0..3
  const int m0   = mi * 32;
  const int og   = oq * 4 + wave;                // this wave's 16-col chunk
  const int lrow = lane & 15, lq = lane >> 4;

  // Cooperative A-build mapping: thread -> (row, 8-col segment of 64).
  const int brow = tid >> 3;                     // 0..31
  const int bseg = tid & 7;                      // cols bseg*8 .. +7
  const int kbi  = bseg >> 2;                    // which kblock of the pair
  const int dsel = (bseg >> 1) & 1;              // which of 2 dims in a kblock
  const float h0 = (float)((bseg & 1) * 8);      // hat base within dim

  // Swizzled LDS offsets (16B slot index ^= row&7): conflict-free-ish reads.
  const int swz   = lrow & 7;
  const int o00   = lrow * 64 + ((lq ^ swz) << 3);          // i=0, kk=0
  const int o01   = lrow * 64 + (((4 | lq) ^ swz) << 3);    // i=0, kk=1
  const int o10   = o00 + 16 * 64;                          // i=1 (row&7 same)
  const int o11   = o01 + 16 * 64;
  const int awoff = brow * 64 + ((bseg ^ (brow & 7)) << 3); // build write

  const uint4* B = (const uint4*)Wf;             // chunk = kb*1024 + og*64 + lane

  floatx4 acc0 = {}, acc1 = {};
  uint4 bb0[2], bb1[2];

  // Stage ALL x dims for this block's 32 rows (16 KB of loads, 33 KB LDS).
  for (int i = tid; i < 32 * 64; i += 256) {
    const int r = i >> 6, c = i & 63;
    *(float4*)&sx[r * SXS + c * 4] = *(const float4*)(x + (size_t)(m0 + r) * Din + c * 4);
  }
  // Prefetch steps 0 and 1 B-frags (no LDS dependency; before barrier).
  bb0[0] = B[(size_t)0 * 1024 + og * 64 + lane];
  bb0[1] = B[(size_t)1 * 1024 + og * 64 + lane];
  bb1[0] = B[(size_t)2 * 1024 + og * 64 + lane];
  bb1[1] = B[(size_t)3 * 1024 + og * 64 + lane];
  __syncthreads();   // sx visible

  // Build A-tile for step 0 (dims 0..3).
  buildA(&aLds[0][awoff], sx[brow * SXS + 2 * kbi + dsel], h0);

  for (int s = 0; s < NSTEP; s += 2) {
    // ---- step s (even, buffers 0) ----
    {
      const uint4 c0 = bb0[0], c1 = bb0[1];
      if (s + 2 < NSTEP) {
        bb0[0] = B[(size_t)(2 * (s + 2)    ) * 1024 + og * 64 + lane];
        bb0[1] = B[(size_t)(2 * (s + 2) + 1) * 1024 + og * 64 + lane];
      }
      __syncthreads();   // aLds[0] writes visible; prior aLds[1] reads done
      // s <= NSTEP-2 here, so s+1 build is always in range.
      buildA(&aLds[1][awoff], sx[brow * SXS + 4 * (s + 1) + 2 * kbi + dsel], h0);
      mstep(aLds[0], c0, c1, o00, o01, o10, o11, acc0, acc1);
    }
    // ---- step s+1 (odd, buffers 1) ----
    {
      const uint4 c0 = bb1[0], c1 = bb1[1];
      if (s + 3 < NSTEP) {
        bb1[0] = B[(size_t)(2 * (s + 3)    ) * 1024 + og * 64 + lane];
        bb1[1] = B[(size_t)(2 * (s + 3) + 1) * 1024 + og * 64 + lane];
      }
      __syncthreads();
      if (s + 2 < NSTEP)
        buildA(&aLds[0][awoff], sx[brow * SXS + 4 * (s + 2) + 2 * kbi + dsel], h0);
      mstep(aLds[1], c0, c1, o00, o01, o10, o11, acc0, acc1);
    }
  }

  // Epilogue: direct out + bias. C/D map: col=lane&15, row=(lane>>4)*4+j.
  const int ocol = og * 16 + lrow;
  const int r0   = m0 + lq * 4;
  const float sb = skip_b[ocol];
  #pragma unroll
  for (int j = 0; j < 4; ++j)
    out[(size_t)(r0 + j) * Dout + ocol] = acc0[j] + sb;
  #pragma unroll
  for (int j = 0; j < 4; ++j)
    out[(size_t)(r0 + 16 + j) * Dout + ocol] = acc1[j] + sb;
}

// ---------------- Fallback (round-1 structure, needs 4.4 MB ws) ----------------
__device__ __forceinline__ void knot_interp(float xraw, float& xv, float& w, int& l) {
  xv = fminf(1.0f, fmaxf(-1.0f, xraw));
  float t = (xv + 1.0f) * INV_H;
  l = (int)ceilf(t) - 1;
  l = l < 0 ? 0 : (l > Kn - 2 ? Kn - 2 : l);
  float g0 = -1.0f + Hgrid * (float)l;
  w = (xv - g0) * INV_H;
}

__global__ __launch_bounds__(256) void prep_transpose(
    const float* __restrict__ values, const float* __restrict__ skip_w,
    float* __restrict__ vt, float* __restrict__ swt) {
  int idx = blockIdx.x * blockDim.x + threadIdx.x;
  if (idx < Din * Kn * Dout) {
    int k = idx & (Kn - 1);
    int d = (idx >> 4) & (Din - 1);
    int o = idx >> 12;
    vt[(d * Kn + k) * Dout + o] = values[idx];
  }
  if (idx < Dout * Din) {
    int d = idx & (Din - 1);
    int o = idx >> 8;
    swt[d * Dout + o] = skip_w[idx];
  }
}

__global__ __launch_bounds__(256) void kan_main(
    const float* __restrict__ x, const float* __restrict__ vt,
    const float* __restrict__ swt, const float* __restrict__ skip_b,
    float* __restrict__ out) {
  __shared__ float s_w[4][Din];
  __shared__ float s_x[4][Din];
  __shared__ int   s_l[4][Din];
  const int tid = threadIdx.x;
  const int b0  = blockIdx.x * 4;
  for (int i = tid; i < 4 * Din; i += 256) {
    int bb = i >> 8;
    int d  = i & (Din - 1);
    float xv, w; int l;
    knot_interp(x[(b0 + bb) * Din + d], xv, w, l);
    s_w[bb][d] = w; s_x[bb][d] = xv; s_l[bb][d] = l;
  }
  __syncthreads();
  const int g = tid >> 6, lane = tid & 63;
  const int o = lane << 2, b = b0 + g;
  float4 acc = make_float4(0.f, 0.f, 0.f, 0.f);
  for (int d = 0; d < Din; ++d) {
    const float w = s_w[g][d], xv = s_x[g][d];
    const int l = s_l[g][d];
    const float* base = vt + (d * Kn + l) * Dout + o;
    const float4 vl = *(const float4*)(base);
    const float4 vr = *(const float4*)(base + Dout);
    const float4 sw = *(const float4*)(swt + d * Dout + o);
    acc.x = fmaf(xv, sw.x, fmaf(w, vr.x - vl.x, acc.x + vl.x));
    acc.y = fmaf(xv, sw.y, fmaf(w, vr.y - vl.y, acc.y + vl.y));
    acc.z = fmaf(xv, sw.z, fmaf(w, vr.z - vl.z, acc.z + vl.z));
    acc.w = fmaf(xv, sw.w, fmaf(w, vr.w - vl.w, acc.w + vl.w));
  }
  const float4 bias = *(const float4*)(skip_b + o);
  acc.x += bias.x; acc.y += bias.y; acc.z += bias.z; acc.w += bias.w;
  *(float4*)(out + (size_t)b * Dout + o) = acc;
}

extern "C" void kernel_launch(void* const* d_in, const int* in_sizes, int n_in,
                              void* d_out, int out_size, void* d_ws, size_t ws_size,
                              hipStream_t stream) {
  (void)in_sizes; (void)n_in; (void)out_size;
  const float* x      = (const float*)d_in[0];
  const float* values = (const float*)d_in[1];
  const float* skip_w = (const float*)d_in[2];
  const float* skip_b = (const float*)d_in[3];
  float* out = (float*)d_out;

  const size_t wf_bytes = (size_t)Dout * KKNOT * sizeof(unsigned short);   // 2.10 MB
  const size_t need_fb  = (size_t)(Din * Kn * Dout + Din * Dout) * sizeof(float);

  if (ws_size >= wf_bytes) {
    unsigned short* Wf = (unsigned short*)d_ws;
    kan_prep<<<(KB * 1024) / 256, 256, 0, stream>>>(values, skip_w, Wf);
    kan_gemm_full<<<256, 256, 0, stream>>>(x, Wf, skip_b, out);
  } else if (ws_size >= need_fb) {
    float* vt  = (float*)d_ws;
    float* swt = vt + Din * Kn * Dout;
    prep_transpose<<<(Din * Kn * Dout + 255) / 256, 256, 0, stream>>>(values, skip_w, vt, swt);
    kan_main<<<Bsz / 4, 256, 0, stream>>>(x, vt, swt, skip_b, out);
  }
}

// Round 4
// 82.926 us; speedup vs baseline: 1.0695x; 1.0695x over previous
//
#include <hip/hip_runtime.h>
#include <hip/hip_bf16.h>

// KANLinear as fragment-direct bf16 MFMA GEMM, 2-kernel + atomic split-K (R4):
//   y = hatA @ W''^T + skip_b
// R3 post-mortem: full-K 32x64 tiles = A-build redundancy x4 (the dominant
//   VALU term) + 1 wave/SIMD (no TLP) => gemm 30us. Reverted to R2's gemm
//   shape: 8 ks x 64 mi = 512 blocks (2/CU), block = 32 rows x 256 cols,
//   redundancy-1 A-build, 8 double-buffered steps.
// R4 change: kan_reduce DELETED. Gemm blocks accumulate into out directly
//   with relaxed device-scope f32 atomicAdd (m20: atomicAdd on global is
//   device-scope by default, NO acq/rel fence => no buffer_wbl2/inv L2
//   writeback+invalidate -- avoids R1's poison). kan_prep pre-initializes
//   out = skip_b broadcast; the prep->gemm launch boundary orders init
//   before accumulation. No partials (16.8MB round-trip gone), no fences.
// Skip fold (verified R1-R3): sum_k hat_k(t)*grid_k = clamp(x) exactly, so
//   prep bakes W''[o][d*16+k] = values[o,d,k] + grid_k*skip_w[o,d] (K=4096).
// A (2048 x 4096) VIRTUAL: per dim d, 16 hat weights max(0,1-|t-k|),
//   t=(clamp(x)+1)*7.5. A tiles (32 x 64) built cooperatively in LDS,
//   double-buffered, 1 barrier/step. W'' PRE-PERMUTED into MFMA B-fragment
//   order (Wf): one coalesced 16B load per 16x32 B-frag per lane.

namespace {
constexpr int Bsz  = 2048;
constexpr int Din  = 256;
constexpr int Dout = 256;
constexpr int Kn   = 16;
constexpr int KKNOT = Din * Kn;        // 4096 = full K (skip folded in)
constexpr int KB    = KKNOT / 32;      // 128 k-blocks of 32
constexpr float INV_H = 7.5f;          // 1 / (2/15)
constexpr float Hgrid = 2.0f / 15.0f;

constexpr int NSPLIT = 8;              // uniform K-splits (16 kblocks each)
constexpr int STK    = 8;              // steps per split (2 kblocks each)
constexpr int SXS    = 36;             // sx row stride (floats) -> conflict-free
}

typedef __attribute__((ext_vector_type(8))) short shortx8;   // 8 bf16 = 4 VGPR
typedef __attribute__((ext_vector_type(4))) float floatx4;   // MFMA acc

__device__ __forceinline__ unsigned int f2bf(float f) {
  __hip_bfloat16 h = __float2bfloat16(f);
  return (unsigned int)*reinterpret_cast<unsigned short*>(&h);
}
__device__ __forceinline__ float clamp1(float v) {
  return fminf(1.f, fmaxf(-1.f, v));
}
// Pack two pre-rounded f32 bit patterns (already +0x8000) into bf16x2.
__device__ __forceinline__ unsigned int packbf(unsigned int e0, unsigned int e1) {
  return (e1 & 0xffff0000u) | (e0 >> 16);
}
__device__ __forceinline__ unsigned int rnd(float f) {
  return __float_as_uint(f) + 0x8000u;
}

// --- Prep: fold skip into values, permute into B-fragment order; ALSO
//     initialize out = skip_b broadcast (gemm atomically accumulates on top).
//     Grid: 512 blocks x 256.  chunk(kb,og,q,n) lane layout matches gemm.
__global__ __launch_bounds__(256) void kan_prep(
    const float* __restrict__ values, const float* __restrict__ skip_w,
    const float* __restrict__ skip_b, unsigned short* __restrict__ Wf,
    float* __restrict__ out) {
  const int tid = blockIdx.x * 256 + threadIdx.x;   // 131072 total
  // out init: 524288 floats = 1 float4/thread; col = (tid*4) & 255.
  {
    const float4 sb = *(const float4*)(skip_b + ((tid << 2) & (Dout - 1)));
    *(float4*)(out + (size_t)tid * 4) = sb;
  }
  const int q  = tid & 3;
  const int n  = (tid >> 2) & 15;
  const int og = (tid >> 6) & 15;
  const int kb = tid >> 10;                          // 0..127
  const int o  = og * 16 + n;
  const int k0 = kb * 32 + q * 8;                    // 8 consecutive k, same dim
  const int d  = k0 >> 4;
  const float h0 = (float)(k0 & 15);                 // 0 or 8
  const float sw = skip_w[o * Din + d];
  const float* src = values + (size_t)o * KKNOT + k0;
  const float4 v0 = *(const float4*)src;
  const float4 v1 = *(const float4*)(src + 4);
  float e[8] = {v0.x, v0.y, v0.z, v0.w, v1.x, v1.y, v1.z, v1.w};
  #pragma unroll
  for (int j = 0; j < 8; ++j)
    e[j] = fmaf(-1.f + (h0 + (float)j) * Hgrid, sw, e[j]);  // + grid_k * skip_w
  const size_t chunk = (size_t)kb * 1024 + og * 64 + q * 16 + n;
  *(uint4*)(Wf + chunk * 8) = make_uint4(
      f2bf(e[0]) | (f2bf(e[1]) << 16), f2bf(e[2]) | (f2bf(e[3]) << 16),
      f2bf(e[4]) | (f2bf(e[5]) << 16), f2bf(e[6]) | (f2bf(e[7]) << 16));
}

// --- GEMM: grid = 8 ks x 64 mi = 512 blocks, 256 thr (4 waves).
//     Block = 32 rows x 256 cols (redundancy-1 A-build), 16 MFMA/step.
//     Epilogue: relaxed f32 atomicAdd into out (device scope, no fences).
__global__ __launch_bounds__(256) void kan_gemm(
    const float* __restrict__ x, const unsigned short* __restrict__ Wf,
    float* __restrict__ out) {
  __shared__ float sx[32 * SXS];                            // x slice, 4.6 KB
  __shared__ __align__(16) unsigned short aLds[2][32 * 64]; // A tiles, 2x4 KB

  const int tid  = threadIdx.x;
  const int wave = tid >> 6, lane = tid & 63;
  const int ks   = blockIdx.x >> 6;              // 0..7
  const int mi   = blockIdx.x & 63;              // 0..63
  const int m0   = mi * 32;
  const int og0  = wave * 4;                     // this wave's 64 out-cols
  const int lrow = lane & 15, lq = lane >> 4;

  // Cooperative A-build mapping: thread -> (row, 8-col segment of 64).
  const int brow = tid >> 3;                     // 0..31
  const int bseg = tid & 7;                      // cols bseg*8 .. +7
  const int kbi  = bseg >> 2;                    // which kblock of the pair
  const int dsel = (bseg >> 1) & 1;              // which of 2 dims in a kblock
  const float h0 = (float)((bseg & 1) * 8);      // hat base within dim

  const uint4* B = (const uint4*)Wf;             // chunk = kb*1024 + og*64 + lane

  floatx4 acc[2][4] = {};
  uint4 bb[2][8];

  const int kb0 = ks * 16;
  const int d0  = ks * 32;
  // Stage x slice: one float4 per thread (row = tid>>3, seg = tid&7).
  {
    const float4 v = *(const float4*)(x + (size_t)(m0 + brow) * Din + d0 + bseg * 4);
    *(float4*)&sx[brow * SXS + bseg * 4] = v;
  }
  __syncthreads();

  // Prolog: prefetch step-0 B-frags (2 kblocks) and build A-tile buf 0.
  #pragma unroll
  for (int kk = 0; kk < 2; ++kk)
    #pragma unroll
    for (int j = 0; j < 4; ++j)
      bb[0][kk * 4 + j] = B[(size_t)(kb0 + kk) * 1024 + (og0 + j) * 64 + lane];
  {
    const float xv = sx[brow * SXS + 2 * kbi + dsel];   // dims 0..3 for s=0
    const float t  = (clamp1(xv) + 1.f) * INV_H;
    unsigned int e[8];
    #pragma unroll
    for (int h = 0; h < 8; ++h)
      e[h] = rnd(fmaxf(0.f, 1.f - fabsf(t - (h0 + (float)h))));
    *(uint4*)&aLds[0][brow * 64 + bseg * 8] =
        make_uint4(packbf(e[0], e[1]), packbf(e[2], e[3]),
                   packbf(e[4], e[5]), packbf(e[6], e[7]));
  }

  for (int s = 0; s < STK; ++s) {
    const int cur = s & 1, nxt = cur ^ 1;
    // Prefetch next step's B-frags (2 kblocks).
    if (s + 1 < STK) {
      #pragma unroll
      for (int kk = 0; kk < 2; ++kk)
        #pragma unroll
        for (int j = 0; j < 4; ++j)
          bb[nxt][kk * 4 + j] =
              B[(size_t)(kb0 + 2 * (s + 1) + kk) * 1024 + (og0 + j) * 64 + lane];
    }
    __syncthreads();   // aLds[cur] visible; prior reads of nxt done

    // Build NEXT A-tile (from LDS sx, no global dependency).
    if (s + 1 < STK) {
      const float xv = sx[brow * SXS + 4 * (s + 1) + 2 * kbi + dsel];
      const float t  = (clamp1(xv) + 1.f) * INV_H;
      unsigned int e[8];
      #pragma unroll
      for (int h = 0; h < 8; ++h)
        e[h] = rnd(fmaxf(0.f, 1.f - fabsf(t - (h0 + (float)h))));
      *(uint4*)&aLds[nxt][brow * 64 + bseg * 8] =
          make_uint4(packbf(e[0], e[1]), packbf(e[2], e[3]),
                     packbf(e[4], e[5]), packbf(e[6], e[7]));
    }

    // A-frags (ds_read_b128) + 16 MFMA.
    shortx8 af[2][2];
    #pragma unroll
    for (int i = 0; i < 2; ++i)
      #pragma unroll
      for (int kk = 0; kk < 2; ++kk)
        af[i][kk] = *(const shortx8*)&aLds[cur][(16 * i + lrow) * 64 + kk * 32 + lq * 8];
    #pragma unroll
    for (int kk = 0; kk < 2; ++kk)
      #pragma unroll
      for (int j = 0; j < 4; ++j) {
        union { uint4 u; shortx8 s; } bc;
        bc.u = bb[cur][kk * 4 + j];
        #pragma unroll
        for (int i = 0; i < 2; ++i)
          acc[i][j] = __builtin_amdgcn_mfma_f32_16x16x32_bf16(af[i][kk], bc.s, acc[i][j], 0, 0, 0);
      }
  }

  // Epilogue: accumulate into out with relaxed device-scope f32 atomicAdd.
  // C/D map: col = (og0+j)*16 + (lane&15); row = m0 + i*16 + (lane>>4)*4 + r.
  // 16 lanes hit 16 consecutive floats per line; 32 atomics/thread at tail.
  #pragma unroll
  for (int i = 0; i < 2; ++i)
    #pragma unroll
    for (int j = 0; j < 4; ++j) {
      const int col  = (og0 + j) * 16 + lrow;
      const int row0 = m0 + i * 16 + lq * 4;
      float* op = out + (size_t)row0 * Dout + col;
      atomicAdd(op,            acc[i][j][0]);
      atomicAdd(op + Dout,     acc[i][j][1]);
      atomicAdd(op + 2 * Dout, acc[i][j][2]);
      atomicAdd(op + 3 * Dout, acc[i][j][3]);
    }
}

// ---------------- Fallback (round-1 structure, needs 4.4 MB ws) ----------------
__device__ __forceinline__ void knot_interp(float xraw, float& xv, float& w, int& l) {
  xv = fminf(1.0f, fmaxf(-1.0f, xraw));
  float t = (xv + 1.0f) * INV_H;
  l = (int)ceilf(t) - 1;
  l = l < 0 ? 0 : (l > Kn - 2 ? Kn - 2 : l);
  float g0 = -1.0f + Hgrid * (float)l;
  w = (xv - g0) * INV_H;
}

__global__ __launch_bounds__(256) void prep_transpose(
    const float* __restrict__ values, const float* __restrict__ skip_w,
    float* __restrict__ vt, float* __restrict__ swt) {
  int idx = blockIdx.x * blockDim.x + threadIdx.x;
  if (idx < Din * Kn * Dout) {
    int k = idx & (Kn - 1);
    int d = (idx >> 4) & (Din - 1);
    int o = idx >> 12;
    vt[(d * Kn + k) * Dout + o] = values[idx];
  }
  if (idx < Dout * Din) {
    int d = idx & (Din - 1);
    int o = idx >> 8;
    swt[d * Dout + o] = skip_w[idx];
  }
}

__global__ __launch_bounds__(256) void kan_main(
    const float* __restrict__ x, const float* __restrict__ vt,
    const float* __restrict__ swt, const float* __restrict__ skip_b,
    float* __restrict__ out) {
  __shared__ float s_w[4][Din];
  __shared__ float s_x[4][Din];
  __shared__ int   s_l[4][Din];
  const int tid = threadIdx.x;
  const int b0  = blockIdx.x * 4;
  for (int i = tid; i < 4 * Din; i += 256) {
    int bb = i >> 8;
    int d  = i & (Din - 1);
    float xv, w; int l;
    knot_interp(x[(b0 + bb) * Din + d], xv, w, l);
    s_w[bb][d] = w; s_x[bb][d] = xv; s_l[bb][d] = l;
  }
  __syncthreads();
  const int g = tid >> 6, lane = tid & 63;
  const int o = lane << 2, b = b0 + g;
  float4 acc = make_float4(0.f, 0.f, 0.f, 0.f);
  for (int d = 0; d < Din; ++d) {
    const float w = s_w[g][d], xv = s_x[g][d];
    const int l = s_l[g][d];
    const float* base = vt + (d * Kn + l) * Dout + o;
    const float4 vl = *(const float4*)(base);
    const float4 vr = *(const float4*)(base + Dout);
    const float4 sw = *(const float4*)(swt + d * Dout + o);
    acc.x = fmaf(xv, sw.x, fmaf(w, vr.x - vl.x, acc.x + vl.x));
    acc.y = fmaf(xv, sw.y, fmaf(w, vr.y - vl.y, acc.y + vl.y));
    acc.z = fmaf(xv, sw.z, fmaf(w, vr.z - vl.z, acc.z + vl.z));
    acc.w = fmaf(xv, sw.w, fmaf(w, vr.w - vl.w, acc.w + vl.w));
  }
  const float4 bias = *(const float4*)(skip_b + o);
  acc.x += bias.x; acc.y += bias.y; acc.z += bias.z; acc.w += bias.w;
  *(float4*)(out + (size_t)b * Dout + o) = acc;
}

extern "C" void kernel_launch(void* const* d_in, const int* in_sizes, int n_in,
                              void* d_out, int out_size, void* d_ws, size_t ws_size,
                              hipStream_t stream) {
  (void)in_sizes; (void)n_in; (void)out_size;
  const float* x      = (const float*)d_in[0];
  const float* values = (const float*)d_in[1];
  const float* skip_w = (const float*)d_in[2];
  const float* skip_b = (const float*)d_in[3];
  float* out = (float*)d_out;

  const size_t wf_bytes = (size_t)Dout * KKNOT * sizeof(unsigned short);   // 2.10 MB
  const size_t need_fb  = (size_t)(Din * Kn * Dout + Din * Dout) * sizeof(float);

  if (ws_size >= wf_bytes) {
    unsigned short* Wf = (unsigned short*)d_ws;
    kan_prep<<<(KB * 1024) / 256, 256, 0, stream>>>(values, skip_w, skip_b, Wf, out);
    kan_gemm<<<64 * NSPLIT, 256, 0, stream>>>(x, Wf, out);
  } else if (ws_size >= need_fb) {
    float* vt  = (float*)d_ws;
    float* swt = vt + Din * Kn * Dout;
    prep_transpose<<<(Din * Kn * Dout + 255) / 256, 256, 0, stream>>>(values, skip_w, vt, swt);
    kan_main<<<Bsz / 4, 256, 0, stream>>>(x, vt, swt, skip_b, out);
  }
}